// Round 6
// baseline (223.424 us; speedup 1.0000x reference)
//
#include <hip/hip_runtime.h>
#include <math.h>

// SCNCore: hidden = sigmoid((concept@Wci^T)*(x@Win^T) + (concept@Wcs^T)*(h@Wst^T))
//          i,f,o,cc = split(hidden,4); c_t = i*cc + f*c_state; h_t = o*tanh(c_t)
// B=1024, IN=H=1024, C=1000, 4H=4096. Inputs fp32, outputs fp32.
//
// R15: SINGLE fused kernel. Six rounds showed total - gemm = ~114us constant:
// the conv_all fp32->bf16 pass + its 77MB round-trip + second launch was never
// attacked. This round deletes it: the GEMM stages fp32 DIRECTLY
// (global_load_dwordx4 x2 -> cvt -> ds_write_b128) producing byte-identical
// swizzled LDS tiles to R13 (elem = i*64 + (slot^(row&7))*8; W-row
// gate-interleave (row>>4)*1024 + bx*16 + (row&15); 1000-col zero-pad inline).
// Compute, epilogue, grid (64,16), 24 KiB LDS, launch_bounds(256,4): R13
// verbatim (51.2us, 0 bank conflicts, 33% occupancy — best measured).
// R14's 32x32 path reverted (7.34M bank conflicts, +7us).

typedef __bf16 bf16_t;
typedef __bf16 bf16x8 __attribute__((ext_vector_type(8)));
typedef float floatx4 __attribute__((ext_vector_type(4)));

#define THREADS 256

__device__ __forceinline__ bf16x8 cvt8(const float4 f0, const float4 f1) {
  bf16x8 v;
  v[0] = (bf16_t)f0.x; v[1] = (bf16_t)f0.y; v[2] = (bf16_t)f0.z; v[3] = (bf16_t)f0.w;
  v[4] = (bf16_t)f1.x; v[5] = (bf16_t)f1.y; v[6] = (bf16_t)f1.z; v[7] = (bf16_t)f1.w;
  return v;
}

// ============================ fp32-direct staging ============================
// Each thread fills 2 x 16B slots of a 64-row x 128B swizzled bf16 tile.
// Slot (row, slot) holds source elems ke0 + (slot^(row&7))*8 .. +7.

// activations x/h: row length 1024, rows M0..M0+63
__device__ __forceinline__ void stageA32(const float* __restrict__ g, int row0,
                                         int ke0, char* s, int tid) {
#pragma unroll
  for (int it = 0; it < 2; ++it) {
    const int flat = it * 4096 + tid * 16;
    const int row  = flat >> 7;
    const int slot = (flat >> 4) & 7;
    const int ke   = ke0 + ((slot ^ (row & 7)) << 3);
    const float* p = g + (size_t)(row0 + row) * 1024 + ke;
    const float4 f0 = *(const float4*)(p);
    const float4 f1 = *(const float4*)(p + 4);
    *(bf16x8*)(s + flat) = cvt8(f0, f1);
  }
}

// concept activations: row length 1000, zero-pad ke >= 1000
__device__ __forceinline__ void stageC32(const float* __restrict__ g, int row0,
                                         int ke0, char* s, int tid) {
#pragma unroll
  for (int it = 0; it < 2; ++it) {
    const int flat = it * 4096 + tid * 16;
    const int row  = flat >> 7;
    const int slot = (flat >> 4) & 7;
    const int ke   = ke0 + ((slot ^ (row & 7)) << 3);
    bf16x8 v;
    if (ke < 1000) {
      const float* p = g + (size_t)(row0 + row) * 1000 + ke;
      const float4 f0 = *(const float4*)(p);
      const float4 f1 = *(const float4*)(p + 4);
      v = cvt8(f0, f1);
    } else {
#pragma unroll
      for (int e = 0; e < 8; ++e) v[e] = (bf16_t)0.f;
    }
    *(bf16x8*)(s + flat) = v;
  }
}

// W tiles: gate-interleaved rows (tile row r -> W row (r>>4)*1024+bx*16+(r&15)),
// row length KW (1024 for Win/Wst, 1000 for Wci/Wcs with zero-pad)
template<int KW>
__device__ __forceinline__ void stageW32(const float* __restrict__ g, int bx,
                                         int ke0, char* s, int tid) {
#pragma unroll
  for (int it = 0; it < 2; ++it) {
    const int flat = it * 4096 + tid * 16;
    const int row  = flat >> 7;
    const int slot = (flat >> 4) & 7;
    const int ke   = ke0 + ((slot ^ (row & 7)) << 3);
    const int wrow = ((row >> 4) << 10) + (bx << 4) + (row & 15);
    bf16x8 v;
    if (KW == 1024 || ke < 1000) {
      const float* p = g + (size_t)wrow * KW + ke;
      const float4 f0 = *(const float4*)(p);
      const float4 f1 = *(const float4*)(p + 4);
      v = cvt8(f0, f1);
    } else {
#pragma unroll
      for (int e = 0; e < 8; ++e) v[e] = (bf16_t)0.f;
    }
    *(bf16x8*)(s + flat) = v;
  }
}

// ============================ compute (R13 verbatim) ============================
__device__ __forceinline__ void compute_block64(const char* sA, const char* sB,
                                                int w, int l15, int quad,
                                                floatx4 (&acc)[4]) {
#pragma unroll
  for (int ks = 0; ks < 2; ++ks) {
    bf16x8 af, bfr[4];
    {
      const int r = w * 16 + l15;
      const int c = (ks * 4 + quad) ^ (r & 7);
      af = *(const bf16x8*)(sA + r * 128 + c * 16);
    }
#pragma unroll
    for (int ni = 0; ni < 4; ++ni) {
      const int r = ni * 16 + l15;
      const int c = (ks * 4 + quad) ^ (r & 7);
      bfr[ni] = *(const bf16x8*)(sB + r * 128 + c * 16);
    }
#pragma unroll
    for (int ni = 0; ni < 4; ++ni)
      acc[ni] = __builtin_amdgcn_mfma_f32_16x16x32_bf16(af, bfr[ni], acc[ni], 0, 0, 0);
  }
}

__device__ __forceinline__ void compute_block2_64(const char* sA, const char* sB1,
                                                  const char* sB2, int w, int l15, int quad,
                                                  floatx4 (&acc1)[4], floatx4 (&acc2)[4]) {
#pragma unroll
  for (int ks = 0; ks < 2; ++ks) {
    bf16x8 af, b1[4], b2[4];
    {
      const int r = w * 16 + l15;
      const int c = (ks * 4 + quad) ^ (r & 7);
      af = *(const bf16x8*)(sA + r * 128 + c * 16);
    }
#pragma unroll
    for (int ni = 0; ni < 4; ++ni) {
      const int r = ni * 16 + l15;
      const int c = (ks * 4 + quad) ^ (r & 7);
      b1[ni] = *(const bf16x8*)(sB1 + r * 128 + c * 16);
      b2[ni] = *(const bf16x8*)(sB2 + r * 128 + c * 16);
    }
#pragma unroll
    for (int ni = 0; ni < 4; ++ni) {
      acc1[ni] = __builtin_amdgcn_mfma_f32_16x16x32_bf16(af, b1[ni], acc1[ni], 0, 0, 0);
      acc2[ni] = __builtin_amdgcn_mfma_f32_16x16x32_bf16(af, b2[ni], acc2[ni], 0, 0, 0);
    }
  }
}

// ============================ fused single kernel (R15) ============================
__global__ __launch_bounds__(THREADS, 4)
void scn_fused(const float* __restrict__ x,   const float* __restrict__ h,
               const float* __restrict__ cpt,
               const float* __restrict__ Win, const float* __restrict__ Wst,
               const float* __restrict__ Wci, const float* __restrict__ Wcs,
               const float* __restrict__ cs, float* __restrict__ out)
{
  __shared__ __align__(16) char sA [64 * 128];  // 8 KiB
  __shared__ __align__(16) char sB1[64 * 128];  // 8 KiB
  __shared__ __align__(16) char sB2[64 * 128];  // 8 KiB  (24 KiB total)
  const int tid = threadIdx.x;
  const int w = tid >> 6, lane = tid & 63, l15 = lane & 15, quad = lane >> 4;
  const int bx = blockIdx.x;           // 16 cols per gate; grid.x = 64
  const int M0 = blockIdx.y * 64;      // batch rows; grid.y = 16

  floatx4 acc0[4], acc1[4], acc2[4];
  const floatx4 z = {0.f, 0.f, 0.f, 0.f};
#pragma unroll
  for (int ni = 0; ni < 4; ++ni) { acc0[ni] = z; acc1[ni] = z; acc2[ni] = z; }

  // phase 1: xi = x @ Win^T -> acc0
  for (int i = 0; i < 16; ++i) {
    const int ke = i * 64;
    __syncthreads();
    stageA32(x, M0, ke, sA, tid);
    stageW32<1024>(Win, bx, ke, sB1, tid);
    __syncthreads();
    compute_block64(sA, sB1, w, l15, quad, acc0);
  }
  // phase 2 (fused dual-B): gi -> acc1, gs -> acc2 (concept staged once)
  for (int i = 0; i < 16; ++i) {
    const int ke = i * 64;
    __syncthreads();
    stageC32(cpt, M0, ke, sA, tid);
    stageW32<1000>(Wci, bx, ke, sB1, tid);
    stageW32<1000>(Wcs, bx, ke, sB2, tid);
    __syncthreads();
    compute_block2_64(sA, sB1, sB2, w, l15, quad, acc1, acc2);
  }
  // P = xi * gi (same C/D fragment layout); recycle acc1 for hs
#pragma unroll
  for (int ni = 0; ni < 4; ++ni) { acc0[ni] = acc0[ni] * acc1[ni]; acc1[ni] = z; }
  // phase 3: hs = h @ Wst^T -> acc1
  for (int i = 0; i < 16; ++i) {
    const int ke = i * 64;
    __syncthreads();
    stageA32(h, M0, ke, sA, tid);
    stageW32<1024>(Wst, bx, ke, sB1, tid);
    __syncthreads();
    compute_block64(sA, sB1, w, l15, quad, acc1);
  }

  // fused LSTM epilogue: e = P + gs*hs; ni = gate {0:i,1:f,2:o,3:cc}
  // C/D layout: row = quad*4 + r, col = l15 (col-within-gate = bx*16 + l15)
#pragma unroll
  for (int r = 0; r < 4; ++r) {
    float g[4];
#pragma unroll
    for (int ni = 0; ni < 4; ++ni) {
      const float e = acc0[ni][r] + acc2[ni][r] * acc1[ni][r];
      g[ni] = 1.f / (1.f + __expf(-e));
    }
    const int row = M0 + w * 16 + quad * 4 + r;
    const int col = (bx << 4) + l15;
    const float cst = cs[(size_t)row * 1024 + col];
    const float ct = g[0] * g[3] + g[1] * cst;
    const float ht = g[2] * tanhf(ct);
    out[(size_t)row * 1024 + col] = ht;
    out[(size_t)(1u << 20) + (size_t)row * 1024 + col] = ct;
  }
}

extern "C" void kernel_launch(void* const* d_in, const int* in_sizes, int n_in,
                              void* d_out, int out_size, void* d_ws, size_t ws_size,
                              hipStream_t stream) {
  (void)in_sizes; (void)n_in; (void)out_size; (void)d_ws; (void)ws_size;
  const float* x   = (const float*)d_in[0];
  const float* h   = (const float*)d_in[1];
  const float* cst = (const float*)d_in[2];
  const float* cpt = (const float*)d_in[3];
  const float* Win = (const float*)d_in[4];
  const float* Wst = (const float*)d_in[5];
  const float* Wci = (const float*)d_in[6];
  const float* Wcs = (const float*)d_in[7];
  float* out = (float*)d_out;

  dim3 grid(64, 16);  // 64 gate-col groups (16 cols x 4 gates) x 16 batch tiles
  scn_fused<<<grid, THREADS, 0, stream>>>(x, h, cpt, Win, Wst, Wci, Wcs, cst, out);
}